// Round 2
// baseline (224.449 us; speedup 1.0000x reference)
//
#include <hip/hip_runtime.h>
#include <hip/hip_bf16.h>
#include <math.h>

typedef __attribute__((ext_vector_type(8))) short bf16x8;
typedef __attribute__((ext_vector_type(4))) float f32x4;

typedef void __attribute__((address_space(1))) gvoid_t;
typedef void __attribute__((address_space(3))) lvoid_t;

#define KP0   1824          // NN_IN (1805) padded to multiple of 32
#define NB    16384         // batch
// workspace layout (bytes)
#define OFF_X    0u
#define OFF_H0   59768832u  // 16384*1824*2
#define OFF_W0T  93323264u  // +16384*1024*2
#define OFF_W1T  97058816u  // +1824*1024*2
#define OFF_FM   98107392u  // +512*1024*2  (W1T is 512*1024*2)

__device__ __forceinline__ float bf2f(short s) {
    return __uint_as_float(((unsigned)(unsigned short)s) << 16);
}

__device__ __forceinline__ void load_lds16(const void* g, void* l) {
    __builtin_amdgcn_global_load_lds(
        (gvoid_t*)(uintptr_t)g,
        (lvoid_t*)(unsigned)(uintptr_t)l,
        16, 0, 0);
}

// ---------------- transpose + cast weights: W (K x N) f32 -> WT (N x KP) bf16, zero-pad k>=K
__global__ __launch_bounds__(256) void transpose_w(const float* __restrict__ W,
                                                   __hip_bfloat16* __restrict__ WT,
                                                   int K, int N, int KP) {
    __shared__ float tile[32][33];
    const int k0 = blockIdx.x * 32, n0 = blockIdx.y * 32;
    const int tx = threadIdx.x, ty = threadIdx.y;
    #pragma unroll
    for (int i = 0; i < 32; i += 8) {
        int k = k0 + ty + i;
        tile[ty + i][tx] = (k < K) ? W[(size_t)k * N + (n0 + tx)] : 0.f;
    }
    __syncthreads();
    #pragma unroll
    for (int i = 0; i < 32; i += 8) {
        int n = n0 + ty + i, k = k0 + tx;
        WT[(size_t)n * KP + k] = __float2bfloat16(tile[tx][ty + i]);
    }
}

// ---------------- gather + FM + build X (bf16, padded K=1824). One wave per batch row.
__global__ __launch_bounds__(256) void gather_fm(const float* __restrict__ dense,
                                                 const int* __restrict__ onehot,
                                                 const int* __restrict__ multihot,
                                                 const float* __restrict__ fm_w,
                                                 const float* __restrict__ fm_emb,
                                                 __hip_bfloat16* __restrict__ X,
                                                 float* __restrict__ FM) {
    const int wv = threadIdx.x >> 6, lane = threadIdx.x & 63;
    const int row = blockIdx.x * 4 + wv;
    const int oh = (lane < 26) ? onehot[row * 26 + lane] : 0;
    const int mh = (lane < 40) ? multihot[row * 40 + lane] : 0;
    const float fm1 = (lane < 26) ? fm_w[oh] : 0.f;
    __hip_bfloat16* Xr = X + (size_t)row * KP0;
    float s = 0.f, sq = 0.f;
    for (int f = 0; f < 26; ++f) {
        int idx = __shfl(oh, f);
        float v = fm_emb[(size_t)idx * 64 + lane];
        s += v; sq += v * v;
        Xr[f * 64 + lane] = __float2bfloat16(v);
    }
    #pragma unroll
    for (int h = 0; h < 2; ++h) {
        float a = 0.f;
        for (int l = 0; l < 20; ++l) {
            int idx = __shfl(mh, h * 20 + l);
            a += fm_emb[(size_t)idx * 64 + lane];
        }
        float v = a * (1.f / 20.f);
        s += v; sq += v * v;
        Xr[(26 + h) * 64 + lane] = __float2bfloat16(v);
    }
    float red = 0.5f * (s * s - sq) + fm1;   // lane-partial fm2 over dim e + fm1 partials
    #pragma unroll
    for (int off = 32; off; off >>= 1) red += __shfl_xor(red, off);
    if (lane == 0) FM[row] = red;
    if (lane < 32) {
        float dv = (lane < 13) ? dense[row * 13 + lane] : 0.f;
        Xr[1792 + lane] = __float2bfloat16(dv);   // 1792..1823 (13 dense + 19 zero pad)
    }
}

// ---------------- GEMM: C(MxN, bf16) = relu(A(MxK) * BT(NxK)^T + bias), lda=ldb=K
__global__ __launch_bounds__(256) void gemm_relu_bf16(const __hip_bfloat16* __restrict__ A,
                                                      const __hip_bfloat16* __restrict__ BT,
                                                      const float* __restrict__ bias,
                                                      __hip_bfloat16* __restrict__ C,
                                                      int M, int N, int K) {
    __shared__ __align__(16) char lds[2][2][8192];   // [dbuf][A/B][128 rows x 32 bf16]
    const int tid = threadIdx.x;
    const int wv = tid >> 6, lane = tid & 63;
    const int lr = lane & 15, lg = lane >> 4;
    const int nbc = N >> 7;
    const int br = blockIdx.x / nbc, bc = blockIdx.x % nbc;
    const int wr = wv >> 1, wc = wv & 1;
    const size_t rowBytes = (size_t)K * 2;

    const char* Ab = (const char*)A + (size_t)(br * 128) * rowBytes;
    const char* Bb = (const char*)BT + (size_t)(bc * 128) * rowBytes;

    const int o0 = wv * 1024 + lane * 16;          // per-lane linear byte offset base
    const int nt = K >> 5;

    auto stage = [&](int buf, int kt) {
        const int k0b = kt * 64;
        #pragma unroll
        for (int i = 0; i < 2; ++i) {
            int o = i * 4096 + o0;
            int r = o >> 6, cb = o & 63;
            load_lds16(Ab + (size_t)r * rowBytes + k0b + cb, &lds[buf][0][i * 4096 + wv * 1024]);
            load_lds16(Bb + (size_t)r * rowBytes + k0b + cb, &lds[buf][1][i * 4096 + wv * 1024]);
        }
    };

    f32x4 acc[4][4] = {};
    stage(0, 0);
    __syncthreads();
    for (int kt = 0; kt < nt; ++kt) {
        const int cur = kt & 1;
        if (kt + 1 < nt) stage(cur ^ 1, kt + 1);   // issue-early; drained by barrier below
        const char* Al = &lds[cur][0][0];
        const char* Bl = &lds[cur][1][0];
        bf16x8 a[4], b[4];
        #pragma unroll
        for (int m = 0; m < 4; ++m)
            a[m] = *(const bf16x8*)(Al + ((wr * 64 + m * 16 + lr) << 6) + (lg << 4));
        #pragma unroll
        for (int n = 0; n < 4; ++n)
            b[n] = *(const bf16x8*)(Bl + ((wc * 64 + n * 16 + lr) << 6) + (lg << 4));
        #pragma unroll
        for (int m = 0; m < 4; ++m)
            #pragma unroll
            for (int n = 0; n < 4; ++n)
                acc[m][n] = __builtin_amdgcn_mfma_f32_16x16x32_bf16(a[m], b[n], acc[m][n], 0, 0, 0);
        __syncthreads();
    }

    const float bv = bias[0];
    const int rowb = br * 128 + wr * 64, colb = bc * 128 + wc * 64;
    #pragma unroll
    for (int m = 0; m < 4; ++m)
        #pragma unroll
        for (int n = 0; n < 4; ++n)
            #pragma unroll
            for (int r = 0; r < 4; ++r) {
                int row = rowb + m * 16 + lg * 4 + r;
                int col = colb + n * 16 + lr;
                C[(size_t)row * N + col] = __float2bfloat16(fmaxf(acc[m][n][r] + bv, 0.f));
            }
}

// ---------------- final: out = sigmoid(FM + relu(H1 . w2 + b2)). One wave per row.
__global__ __launch_bounds__(256) void final_k(const __hip_bfloat16* __restrict__ H1,
                                               const float* __restrict__ w2,
                                               const float* __restrict__ b2,
                                               const float* __restrict__ FM,
                                               float* __restrict__ out) {
    const int wv = threadIdx.x >> 6, lane = threadIdx.x & 63;
    const int row = blockIdx.x * 4 + wv;
    const bf16x8 h = *(const bf16x8*)(H1 + (size_t)row * 512 + lane * 8);
    float s = 0.f;
    #pragma unroll
    for (int j = 0; j < 8; ++j) s += bf2f(h[j]) * w2[lane * 8 + j];
    #pragma unroll
    for (int off = 32; off; off >>= 1) s += __shfl_xor(s, off);
    if (lane == 0) {
        float v = fmaxf(s + b2[0], 0.f) + FM[row];
        out[row] = 1.f / (1.f + expf(-v));
    }
}

extern "C" void kernel_launch(void* const* d_in, const int* in_sizes, int n_in,
                              void* d_out, int out_size, void* d_ws, size_t ws_size,
                              hipStream_t stream) {
    const float* dense    = (const float*)d_in[0];
    const int*   onehot   = (const int*)d_in[1];
    const int*   multihot = (const int*)d_in[2];
    const float* fm_w     = (const float*)d_in[3];
    const float* fm_emb   = (const float*)d_in[4];
    const float* w0       = (const float*)d_in[5];
    const float* b0       = (const float*)d_in[6];
    const float* w1       = (const float*)d_in[7];
    const float* b1       = (const float*)d_in[8];
    const float* w2       = (const float*)d_in[9];
    const float* b2       = (const float*)d_in[10];
    float* out = (float*)d_out;

    char* ws = (char*)d_ws;
    __hip_bfloat16* X   = (__hip_bfloat16*)(ws + OFF_X);
    __hip_bfloat16* H1  = (__hip_bfloat16*)(ws + OFF_X);      // aliases X (dead after GEMM0)
    __hip_bfloat16* H0  = (__hip_bfloat16*)(ws + OFF_H0);
    __hip_bfloat16* W0T = (__hip_bfloat16*)(ws + OFF_W0T);
    __hip_bfloat16* W1T = (__hip_bfloat16*)(ws + OFF_W1T);
    float*          FM  = (float*)(ws + OFF_FM);

    transpose_w<<<dim3(57, 32), dim3(32, 8), 0, stream>>>(w0, W0T, 1805, 1024, KP0);
    transpose_w<<<dim3(32, 16), dim3(32, 8), 0, stream>>>(w1, W1T, 1024, 512, 1024);
    gather_fm<<<NB / 4, 256, 0, stream>>>(dense, onehot, multihot, fm_w, fm_emb, X, FM);
    gemm_relu_bf16<<<(NB / 128) * (1024 / 128), 256, 0, stream>>>(X,  W0T, b0, H0, NB, 1024, KP0);
    gemm_relu_bf16<<<(NB / 128) * (512 / 128),  256, 0, stream>>>(H0, W1T, b1, H1, NB, 512, 1024);
    final_k<<<NB / 4, 256, 0, stream>>>(H1, w2, b2, FM, out);
}

// Round 3
// 177.998 us; speedup vs baseline: 1.2610x; 1.2610x over previous
//
#include <hip/hip_runtime.h>
#include <hip/hip_bf16.h>
#include <math.h>

typedef __attribute__((ext_vector_type(8))) short bf16x8;
typedef __attribute__((ext_vector_type(4))) float f32x4;

typedef void __attribute__((address_space(1))) gvoid_t;
typedef void __attribute__((address_space(3))) lvoid_t;

#define KP0   1824          // NN_IN (1805) padded to multiple of 32
#define NB    16384         // batch
// workspace layout (bytes)
#define OFF_X    0u
#define OFF_H0   59768832u  // 16384*1824*2
#define OFF_W0T  93323264u  // +16384*1024*2
#define OFF_W1T  97058816u  // +1824*1024*2
#define OFF_FM   98107392u  // +512*1024*2  (W1T is 512*1024*2)

#define VMCNT(n) asm volatile("s_waitcnt vmcnt(" #n ")" ::: "memory")

__device__ __forceinline__ float bf2f(short s) {
    return __uint_as_float(((unsigned)(unsigned short)s) << 16);
}

__device__ __forceinline__ void load_lds16(const void* g, void* l) {
    __builtin_amdgcn_global_load_lds(
        (gvoid_t*)(uintptr_t)g,
        (lvoid_t*)(unsigned)(uintptr_t)l,
        16, 0, 0);
}

// ---------------- transpose + cast weights: W (K x N) f32 -> WT (N x KP) bf16, zero-pad k>=K
__global__ __launch_bounds__(256) void transpose_w(const float* __restrict__ W,
                                                   __hip_bfloat16* __restrict__ WT,
                                                   int K, int N, int KP) {
    __shared__ float tile[32][33];
    const int k0 = blockIdx.x * 32, n0 = blockIdx.y * 32;
    const int tx = threadIdx.x, ty = threadIdx.y;
    #pragma unroll
    for (int i = 0; i < 32; i += 8) {
        int k = k0 + ty + i;
        tile[ty + i][tx] = (k < K) ? W[(size_t)k * N + (n0 + tx)] : 0.f;
    }
    __syncthreads();
    #pragma unroll
    for (int i = 0; i < 32; i += 8) {
        int n = n0 + ty + i, k = k0 + tx;
        WT[(size_t)n * KP + k] = __float2bfloat16(tile[tx][ty + i]);
    }
}

// ---------------- gather + FM + build X (bf16, padded K=1824). One wave per batch row.
__global__ __launch_bounds__(256) void gather_fm(const float* __restrict__ dense,
                                                 const int* __restrict__ onehot,
                                                 const int* __restrict__ multihot,
                                                 const float* __restrict__ fm_w,
                                                 const float* __restrict__ fm_emb,
                                                 __hip_bfloat16* __restrict__ X,
                                                 float* __restrict__ FM) {
    const int wv = threadIdx.x >> 6, lane = threadIdx.x & 63;
    const int row = blockIdx.x * 4 + wv;
    const int oh = (lane < 26) ? onehot[row * 26 + lane] : 0;
    const int mh = (lane < 40) ? multihot[row * 40 + lane] : 0;
    const float fm1 = (lane < 26) ? fm_w[oh] : 0.f;
    __hip_bfloat16* Xr = X + (size_t)row * KP0;
    float s = 0.f, sq = 0.f;
    for (int f = 0; f < 26; ++f) {
        int idx = __shfl(oh, f);
        float v = fm_emb[(size_t)idx * 64 + lane];
        s += v; sq += v * v;
        Xr[f * 64 + lane] = __float2bfloat16(v);
    }
    #pragma unroll
    for (int h = 0; h < 2; ++h) {
        float a = 0.f;
        for (int l = 0; l < 20; ++l) {
            int idx = __shfl(mh, h * 20 + l);
            a += fm_emb[(size_t)idx * 64 + lane];
        }
        float v = a * (1.f / 20.f);
        s += v; sq += v * v;
        Xr[(26 + h) * 64 + lane] = __float2bfloat16(v);
    }
    float red = 0.5f * (s * s - sq) + fm1;   // lane-partial fm2 over dim e + fm1 partials
    #pragma unroll
    for (int off = 32; off; off >>= 1) red += __shfl_xor(red, off);
    if (lane == 0) FM[row] = red;
    if (lane < 32) {
        float dv = (lane < 13) ? dense[row * 13 + lane] : 0.f;
        Xr[1792 + lane] = __float2bfloat16(dv);   // 1792..1823 (13 dense + 19 zero pad)
    }
}

// ---------------- pipelined GEMM: C(MxN,bf16) = relu(A(MxK) * BT(NxK)^T + bias)
// BM=256, BN=NREP*64, BK=32. 8 waves (2Mx4N), per-wave 128 x NREP*16.
// 4-deep LDS pipeline, counted vmcnt, raw s_barrier, XOR slot swizzle, setprio.
// Requires: M%256==0, N%BN==0, K%32==0, K/32>=3, grid = (M/256)*(N/BN) with N/BN==4.
template<int NREP>
__global__ __launch_bounds__(512, 2) void gemm_pipe(const __hip_bfloat16* __restrict__ A,
                                                    const __hip_bfloat16* __restrict__ BT,
                                                    const float* __restrict__ bias,
                                                    __hip_bfloat16* __restrict__ C,
                                                    int M, int N, int K) {
    constexpr int BBY = NREP * 4096;            // B-region bytes per buffer
    __shared__ __align__(16) char lds[4][16384 + BBY];
    const int tid = threadIdx.x;
    const int wv = tid >> 6, lane = tid & 63;
    const int lr = lane & 15, lg = lane >> 4;
    const int wr = wv >> 2, wc = wv & 3;

    // XCD-chunked block swizzle (grid == 256, 8 XCDs -> 32 consecutive wg per XCD)
    const int bid = blockIdx.x;
    const int wg = (bid & 7) * 32 + (bid >> 3);
    const int br = wg >> 2, bc = wg & 3;

    const size_t rowBytes = (size_t)K * 2;
    const char* Ab = (const char*)A + (size_t)(br * 256) * rowBytes;
    const char* Bb = (const char*)BT + (size_t)(bc * (NREP * 64)) * rowBytes;
    const int nt = K >> 5;

    auto stage = [&](int kt) {
        const int buf = kt & 3;
        const size_t kb = (size_t)kt * 64;
        #pragma unroll
        for (int i = 0; i < 2; ++i) {          // A: 256 rows x 64B
            int o = i * 8192 + wv * 1024 + lane * 16;
            int row = o >> 6, slot = (o >> 4) & 3;
            int sg = slot ^ ((row >> 1) & 3);
            load_lds16(Ab + (size_t)row * rowBytes + kb + sg * 16,
                       &lds[buf][i * 8192 + wv * 1024]);
        }
        #pragma unroll
        for (int i = 0; i < NREP / 2; ++i) {   // B: NREP*64 rows x 64B
            int o = i * 8192 + wv * 1024 + lane * 16;
            int row = o >> 6, slot = (o >> 4) & 3;
            int sg = slot ^ ((row >> 1) & 3);
            load_lds16(Bb + (size_t)row * rowBytes + kb + sg * 16,
                       &lds[buf][16384 + i * 8192 + wv * 1024]);
        }
    };

    f32x4 acc[8][NREP] = {};

    // prologue: stage tiles 0..2, wait tile 0 (2L loads still in flight), barrier
    stage(0); stage(1); stage(2);
    if constexpr (NREP == 4) VMCNT(8); else VMCNT(6);
    __builtin_amdgcn_s_barrier();
    __builtin_amdgcn_sched_barrier(0);

    const int swz = ((lr >> 1) & 3) << 4;      // per-lane read-side XOR (matches source pre-swizzle)
    const int aoff0 = (wr * 128 + lr) * 64 + ((lg << 4) ^ swz);
    const int boff0 = 16384 + (wc * (NREP * 16) + lr) * 64 + ((lg << 4) ^ swz);

    for (int kt = 0; kt < nt; ++kt) {
        if (kt + 3 < nt) stage(kt + 3);
        __builtin_amdgcn_sched_barrier(0);

        const char* base = lds[kt & 3];
        bf16x8 a[8], b[NREP];
        #pragma unroll
        for (int m = 0; m < 8; ++m)
            a[m] = *(const bf16x8*)(base + aoff0 + m * 1024);
        #pragma unroll
        for (int n = 0; n < NREP; ++n)
            b[n] = *(const bf16x8*)(base + boff0 + n * 1024);

        __builtin_amdgcn_s_setprio(1);
        #pragma unroll
        for (int m = 0; m < 8; ++m)
            #pragma unroll
            for (int n = 0; n < NREP; ++n)
                acc[m][n] = __builtin_amdgcn_mfma_f32_16x16x32_bf16(a[m], b[n], acc[m][n], 0, 0, 0);
        __builtin_amdgcn_s_setprio(0);

        if (kt + 1 < nt) {
            asm volatile("s_waitcnt lgkmcnt(0)" ::: "memory");
            if (kt + 3 < nt)      { if constexpr (NREP == 4) VMCNT(8); else VMCNT(6); }
            else if (kt + 2 < nt) { if constexpr (NREP == 4) VMCNT(4); else VMCNT(3); }
            else                  { VMCNT(0); }
            __builtin_amdgcn_s_barrier();
            __builtin_amdgcn_sched_barrier(0);
        }
    }

    const float bv = bias[0];
    const int rowb = br * 256 + wr * 128, colb = bc * (NREP * 64) + wc * (NREP * 16);
    #pragma unroll
    for (int m = 0; m < 8; ++m)
        #pragma unroll
        for (int n = 0; n < NREP; ++n)
            #pragma unroll
            for (int r = 0; r < 4; ++r) {
                int row = rowb + m * 16 + lg * 4 + r;
                int col = colb + n * 16 + lr;
                C[(size_t)row * N + col] = __float2bfloat16(fmaxf(acc[m][n][r] + bv, 0.f));
            }
}

// ---------------- final: out = sigmoid(FM + relu(H1 . w2 + b2)). One wave per row.
__global__ __launch_bounds__(256) void final_k(const __hip_bfloat16* __restrict__ H1,
                                               const float* __restrict__ w2,
                                               const float* __restrict__ b2,
                                               const float* __restrict__ FM,
                                               float* __restrict__ out) {
    const int wv = threadIdx.x >> 6, lane = threadIdx.x & 63;
    const int row = blockIdx.x * 4 + wv;
    const bf16x8 h = *(const bf16x8*)(H1 + (size_t)row * 512 + lane * 8);
    float s = 0.f;
    #pragma unroll
    for (int j = 0; j < 8; ++j) s += bf2f(h[j]) * w2[lane * 8 + j];
    #pragma unroll
    for (int off = 32; off; off >>= 1) s += __shfl_xor(s, off);
    if (lane == 0) {
        float v = fmaxf(s + b2[0], 0.f) + FM[row];
        out[row] = 1.f / (1.f + expf(-v));
    }
}

extern "C" void kernel_launch(void* const* d_in, const int* in_sizes, int n_in,
                              void* d_out, int out_size, void* d_ws, size_t ws_size,
                              hipStream_t stream) {
    const float* dense    = (const float*)d_in[0];
    const int*   onehot   = (const int*)d_in[1];
    const int*   multihot = (const int*)d_in[2];
    const float* fm_w     = (const float*)d_in[3];
    const float* fm_emb   = (const float*)d_in[4];
    const float* w0       = (const float*)d_in[5];
    const float* b0       = (const float*)d_in[6];
    const float* w1       = (const float*)d_in[7];
    const float* b1       = (const float*)d_in[8];
    const float* w2       = (const float*)d_in[9];
    const float* b2       = (const float*)d_in[10];
    float* out = (float*)d_out;

    char* ws = (char*)d_ws;
    __hip_bfloat16* X   = (__hip_bfloat16*)(ws + OFF_X);
    __hip_bfloat16* H1  = (__hip_bfloat16*)(ws + OFF_X);      // aliases X (dead after GEMM0)
    __hip_bfloat16* H0  = (__hip_bfloat16*)(ws + OFF_H0);
    __hip_bfloat16* W0T = (__hip_bfloat16*)(ws + OFF_W0T);
    __hip_bfloat16* W1T = (__hip_bfloat16*)(ws + OFF_W1T);
    float*          FM  = (float*)(ws + OFF_FM);

    transpose_w<<<dim3(57, 32), dim3(32, 8), 0, stream>>>(w0, W0T, 1805, 1024, KP0);
    transpose_w<<<dim3(32, 16), dim3(32, 8), 0, stream>>>(w1, W1T, 1024, 512, 1024);
    gather_fm<<<NB / 4, 256, 0, stream>>>(dense, onehot, multihot, fm_w, fm_emb, X, FM);
    gemm_pipe<4><<<256, 512, 0, stream>>>(X,  W0T, b0, H0, NB, 1024, KP0);   // 64 x 4 blocks of 256x256
    gemm_pipe<2><<<256, 512, 0, stream>>>(H0, W1T, b1, H1, NB, 512, 1024);   // 64 x 4 blocks of 256x128
    final_k<<<NB / 4, 256, 0, stream>>>(H1, w2, b2, FM, out);
}